// Round 7
// baseline (106.233 us; speedup 1.0000x reference)
//
#include <hip/hip_runtime.h>
#include <hip/hip_bf16.h>
#include <math.h>

#define BB 16
#define CC 128
#define NN 2048
#define CQ 32   // C/4

typedef __attribute__((ext_vector_type(8))) short bf16x8;
typedef __attribute__((ext_vector_type(4))) float f32x4;

__device__ __forceinline__ ushort f2b(float f) {
    __hip_bfloat16 h = __float2bfloat16(f);
    return *reinterpret_cast<ushort*>(&h);
}
__device__ __forceinline__ float b2f(ushort u) {
    union { unsigned u; float f; } v; v.u = ((unsigned)u) << 16;
    return v.f;
}

// ---------------- workspace layout (float granularity offsets) ----------------
// Qt  : bf16 [B][N][32]   off 0          (524,288 fl)
// Vb  : bf16 [B][128][N]  off 524,288    (2,097,152 fl)
// XRb : bf16 [B][128][N]  off 2,621,440  (2,097,152 fl)
// RSI : f32  [B][N]       off 4,718,592  (32,768 fl)
#define OFF_VB  524288
#define OFF_XRB 2621440
#define OFF_RSI 4718592

// K1: MFMA projection. Qt[b,n,d] (d<32), Vb[b,d,n] = wv.x + bv.
// Weights cast f32->bf16 into LDS in-kernel (k_wprep folded away).
__global__ __launch_bounds__(256) void k_proj(const float* __restrict__ x,
        const float* __restrict__ wq, const float* __restrict__ wv,
        const float* __restrict__ bv, ushort* __restrict__ Qt, ushort* __restrict__ Vb) {
    __shared__ ushort Wl[160][136];
    __shared__ ushort Xs[64][136];   // [n][c] bf16
    int bid = (blockIdx.x & 7) * 64 + (blockIdx.x >> 3);   // XCD-chunked swizzle
    int b  = bid >> 5;
    int n0 = (bid & 31) << 6;
    int tid = threadIdx.x;
    #pragma unroll
    for (int k = 0; k < 20; ++k) {
        int idx = k * 256 + tid;          // 5120 float4 chunks = 160x128 f32
        int r = idx >> 5, c4 = (idx & 31) << 2;
        const float* srcw = (r < 32) ? (wq + r * 128 + c4) : (wv + (r - 32) * 128 + c4);
        float4 w4 = *(const float4*)srcw;
        *(ushort4*)&Wl[r][c4] = make_ushort4(f2b(w4.x), f2b(w4.y), f2b(w4.z), f2b(w4.w));
    }
    const float* xb = x + (size_t)b * CC * NN;
    for (int idx = tid; idx < 2048; idx += 256) {
        int c = idx >> 4, n4 = (idx & 15) << 2;
        float4 xv = *(const float4*)&xb[c * NN + n0 + n4];
        Xs[n4][c]     = f2b(xv.x);
        Xs[n4 + 1][c] = f2b(xv.y);
        Xs[n4 + 2][c] = f2b(xv.z);
        Xs[n4 + 3][c] = f2b(xv.w);
    }
    __syncthreads();
    int w = tid >> 6, l = tid & 63, lr = l & 15, lg = l >> 4;
    f32x4 zero = {0.f, 0.f, 0.f, 0.f};
    int nn = n0 + w * 16 + lr;
    for (int dt = 0; dt < 10; ++dt) {
        f32x4 acc = zero;
        #pragma unroll
        for (int k = 0; k < 4; ++k) {
            bf16x8 a  = *(const bf16x8*)&Wl[dt * 16 + lr][k * 32 + lg * 8];
            bf16x8 bx = *(const bf16x8*)&Xs[w * 16 + lr][k * 32 + lg * 8];
            acc = __builtin_amdgcn_mfma_f32_16x16x32_bf16(a, bx, acc, 0, 0, 0);
        }
        if (dt < 2) {
            ushort4 p = make_ushort4(f2b(acc[0]), f2b(acc[1]), f2b(acc[2]), f2b(acc[3]));
            *(ushort4*)&Qt[(size_t)(b * NN + nn) * CQ + dt * 16 + lg * 4] = p;
        } else {
            #pragma unroll
            for (int i = 0; i < 4; ++i) {
                int vd = (dt - 2) * 16 + lg * 4 + i;
                Vb[(size_t)(b * CC + vd) * NN + nn] = f2b(acc[i] + bv[vd]);
            }
        }
    }
}

// K2: row softmax denominators (no max-subtract; E bounded). RSI = 1/rowsum.
// 512 thr / 8 waves: wave = (n-strip wn, m-half wm).
__global__ __launch_bounds__(512) void k_rowstats(const ushort* __restrict__ Qt,
        float* __restrict__ RSI) {
    __shared__ ushort Qm[128][36];   // [m][k], stride 36 -> conflict-free frag reads
    __shared__ float Sred[2][64];
    int bid = (blockIdx.x & 7) * 64 + (blockIdx.x >> 3);
    int b  = bid >> 5;
    int n0 = (bid & 31) << 6;
    int tid = threadIdx.x;
    int w = tid >> 6, l = tid & 63, lr = l & 15, lg = l >> 4;
    int wn = w & 3, wm = w >> 2;
    const ushort* Qtb = Qt + (size_t)b * NN * CQ;
    bf16x8 aq = *(const bf16x8*)&Qtb[(size_t)(n0 + wn * 16 + lr) * CQ + lg * 8];
    int sr = tid >> 2, sc = (tid & 3) * 8;
    uint4 q0 = *(const uint4*)&Qtb[(size_t)sr * CQ + sc];
    float S[4] = {0.f, 0.f, 0.f, 0.f};
    f32x4 zero = {0.f, 0.f, 0.f, 0.f};
    for (int t = 0; t < 16; ++t) {
        __syncthreads();
        *(uint4*)&Qm[sr][sc] = q0;
        __syncthreads();
        if (t < 15)
            q0 = *(const uint4*)&Qtb[(size_t)((t + 1) * 128 + sr) * CQ + sc];
        #pragma unroll
        for (int mi = 0; mi < 4; ++mi) {
            bf16x8 bq = *(const bf16x8*)&Qm[(wm * 4 + mi) * 16 + lr][lg * 8];
            f32x4 e = __builtin_amdgcn_mfma_f32_16x16x32_bf16(aq, bq, zero, 0, 0, 0);
            S[0] += __expf(e[0]); S[1] += __expf(e[1]);
            S[2] += __expf(e[2]); S[3] += __expf(e[3]);
        }
    }
    #pragma unroll
    for (int d = 1; d < 16; d <<= 1) {
        #pragma unroll
        for (int i = 0; i < 4; ++i) S[i] += __shfl_xor(S[i], d);
    }
    if (lr == 0) {
        #pragma unroll
        for (int i = 0; i < 4; ++i) Sred[wm][wn * 16 + lg * 4 + i] = S[i];
    }
    __syncthreads();
    if (tid < 64)
        RSI[b * NN + n0 + tid] = 1.f / (Sred[0][tid] + Sred[1][tid]);
}

// K3: attn + PV. m-tile 32, 1024 blocks, 512 thr, 2 barriers/iter.
// E: bm[2] in regs, aq from global. V fragments straight from global (L2-hot).
// Ws (32x128 bf16) is the only staged tile.
__global__ __launch_bounds__(512, 8) void k_attn_pv(const ushort* __restrict__ Qt,
        const ushort* __restrict__ Vb, const float* __restrict__ RSI,
        ushort* __restrict__ XRb) {
    __shared__ ushort Ws[32][132];   // [m][n]
    __shared__ float csred[8][32];
    __shared__ float csum[32];
    int bid = (blockIdx.x & 7) * 128 + (blockIdx.x >> 3);  // XCD-chunked swizzle
    int b  = bid >> 6;
    int m0 = (bid & 63) << 5;
    int tid = threadIdx.x;
    int w = tid >> 6, l = tid & 63, lr = l & 15, lg = l >> 4;
    const ushort* Qtb = Qt + (size_t)b * NN * CQ;
    const ushort* Vbb = Vb + (size_t)b * CC * NN;
    const float*  RSb = RSI + (size_t)b * NN;
    bf16x8 bm0 = *(const bf16x8*)&Qtb[(size_t)(m0 + lr) * CQ + lg * 8];
    bf16x8 bm1 = *(const bf16x8*)&Qtb[(size_t)(m0 + 16 + lr) * CQ + lg * 8];
    f32x4 zero = {0.f, 0.f, 0.f, 0.f};
    f32x4 pacc0 = zero, pacc1 = zero;
    float cs0 = 0.f, cs1 = 0.f;
    for (int t = 0; t < 16; ++t) {
        int nt = t * 128;
        bf16x8 aq = *(const bf16x8*)&Qtb[(size_t)(nt + w * 16 + lr) * CQ + lg * 8];
        float4 rsi4 = *(const float4*)&RSb[nt + w * 16 + lg * 4];
        __syncthreads();                     // (a) prev PV done reading Ws
        f32x4 e0 = __builtin_amdgcn_mfma_f32_16x16x32_bf16(aq, bm0, zero, 0, 0, 0);
        f32x4 e1 = __builtin_amdgcn_mfma_f32_16x16x32_bf16(aq, bm1, zero, 0, 0, 0);
        int nb = w * 16 + lg * 4;
        {
            float w0 = __expf(e0[0]) * rsi4.x;
            float w1 = __expf(e0[1]) * rsi4.y;
            float w2 = __expf(e0[2]) * rsi4.z;
            float w3 = __expf(e0[3]) * rsi4.w;
            cs0 += w0 + w1 + w2 + w3;
            *(ushort4*)&Ws[lr][nb] = make_ushort4(f2b(w0), f2b(w1), f2b(w2), f2b(w3));
        }
        {
            float w0 = __expf(e1[0]) * rsi4.x;
            float w1 = __expf(e1[1]) * rsi4.y;
            float w2 = __expf(e1[2]) * rsi4.z;
            float w3 = __expf(e1[3]) * rsi4.w;
            cs1 += w0 + w1 + w2 + w3;
            *(ushort4*)&Ws[16 + lr][nb] = make_ushort4(f2b(w0), f2b(w1), f2b(w2), f2b(w3));
        }
        __syncthreads();                     // (b) Ws ready
        // PV: wave w owns d-strip [16w, 16w+16); va straight from global
        #pragma unroll
        for (int kk = 0; kk < 4; ++kk) {
            bf16x8 va = *(const bf16x8*)&Vbb[(size_t)(w * 16 + lr) * NN + nt + kk * 32 + lg * 8];
            bf16x8 wb0 = *(const bf16x8*)&Ws[lr][kk * 32 + lg * 8];
            bf16x8 wb1 = *(const bf16x8*)&Ws[16 + lr][kk * 32 + lg * 8];
            pacc0 = __builtin_amdgcn_mfma_f32_16x16x32_bf16(va, wb0, pacc0, 0, 0, 0);
            pacc1 = __builtin_amdgcn_mfma_f32_16x16x32_bf16(va, wb1, pacc1, 0, 0, 0);
        }
    }
    // column sums: reduce over lg (shfl), then over 8 waves (LDS)
    cs0 += __shfl_xor(cs0, 16); cs0 += __shfl_xor(cs0, 32);
    cs1 += __shfl_xor(cs1, 16); cs1 += __shfl_xor(cs1, 32);
    if (lg == 0) {
        csred[w][lr]      = cs0;
        csred[w][16 + lr] = cs1;
    }
    __syncthreads();
    if (tid < 32) {
        float tot = 0.f;
        #pragma unroll
        for (int w2 = 0; w2 < 8; ++w2) tot += csred[w2][tid];
        csum[tid] = 1.f / (1e-9f + tot);
    }
    __syncthreads();
    float inv0 = csum[lr], inv1 = csum[16 + lr];
    #pragma unroll
    for (int i = 0; i < 4; ++i) {
        int d = w * 16 + lg * 4 + i;
        XRb[(size_t)(b * CC + d) * NN + m0 + lr]      = f2b(pacc0[i] * inv0);
        XRb[(size_t)(b * CC + d) * NN + m0 + 16 + lr] = f2b(pacc1[i] * inv1);
    }
}

// K4: MFMA final: t = wt @ (x - XR); out = x + relu(t*fA + fB).
// Weights cast in-kernel; fA/fB computed per block.
__global__ __launch_bounds__(256) void k_final(const float* __restrict__ x,
        const ushort* __restrict__ XRb, const float* __restrict__ wt,
        const float* __restrict__ bt, const float* __restrict__ gamma,
        const float* __restrict__ beta, const float* __restrict__ bn_mean,
        const float* __restrict__ bn_var, float* __restrict__ out) {
    __shared__ ushort Wl[128][136];
    __shared__ ushort Us[64][136];   // [n][c] bf16
    __shared__ float fAl[128], fBl[128];
    int bid = (blockIdx.x & 7) * 64 + (blockIdx.x >> 3);
    int b  = bid >> 5;
    int n0 = (bid & 31) << 6;
    int tid = threadIdx.x;
    #pragma unroll
    for (int k = 0; k < 16; ++k) {
        int idx = k * 256 + tid;          // 4096 float4 = 128x128 f32
        int r = idx >> 5, c4 = (idx & 31) << 2;
        float4 w4 = *(const float4*)&wt[r * 128 + c4];
        *(ushort4*)&Wl[r][c4] = make_ushort4(f2b(w4.x), f2b(w4.y), f2b(w4.z), f2b(w4.w));
    }
    if (tid < 128) {
        float A = gamma[tid] * rsqrtf(bn_var[tid] + 1e-5f);
        fAl[tid] = A;
        fBl[tid] = (bt[tid] - bn_mean[tid]) * A + beta[tid];
    }
    const float*  xb  = x   + (size_t)b * CC * NN;
    const ushort* xrb = XRb + (size_t)b * CC * NN;
    for (int idx = tid; idx < 2048; idx += 256) {
        int c = idx >> 4, n4 = (idx & 15) << 2;
        float4 xv = *(const float4*)&xb[c * NN + n0 + n4];
        ushort4 rv = *(const ushort4*)&xrb[c * NN + n0 + n4];
        Us[n4][c]     = f2b(xv.x - b2f(rv.x));
        Us[n4 + 1][c] = f2b(xv.y - b2f(rv.y));
        Us[n4 + 2][c] = f2b(xv.z - b2f(rv.z));
        Us[n4 + 3][c] = f2b(xv.w - b2f(rv.w));
    }
    __syncthreads();
    int w = tid >> 6, l = tid & 63, lr = l & 15, lg = l >> 4;
    f32x4 zero = {0.f, 0.f, 0.f, 0.f};
    int nn = n0 + w * 16 + lr;
    for (int dt = 0; dt < 8; ++dt) {
        f32x4 acc = zero;
        #pragma unroll
        for (int k = 0; k < 4; ++k) {
            bf16x8 a  = *(const bf16x8*)&Wl[dt * 16 + lr][k * 32 + lg * 8];
            bf16x8 bx = *(const bf16x8*)&Us[w * 16 + lr][k * 32 + lg * 8];
            acc = __builtin_amdgcn_mfma_f32_16x16x32_bf16(a, bx, acc, 0, 0, 0);
        }
        #pragma unroll
        for (int i = 0; i < 4; ++i) {
            int r = dt * 16 + lg * 4 + i;
            float t = acc[i] * fAl[r] + fBl[r];
            t = fmaxf(t, 0.f);
            out[(size_t)(b * CC + r) * NN + nn] = xb[r * NN + nn] + t;
        }
    }
}

extern "C" void kernel_launch(void* const* d_in, const int* in_sizes, int n_in,
                              void* d_out, int out_size, void* d_ws, size_t ws_size,
                              hipStream_t stream) {
    const float* x       = (const float*)d_in[0];
    const float* wq      = (const float*)d_in[1];
    const float* wv      = (const float*)d_in[2];
    const float* bv      = (const float*)d_in[3];
    const float* wt      = (const float*)d_in[4];
    const float* bt      = (const float*)d_in[5];
    const float* gamma   = (const float*)d_in[6];
    const float* beta    = (const float*)d_in[7];
    const float* bn_mean = (const float*)d_in[8];
    const float* bn_var  = (const float*)d_in[9];
    float* out = (float*)d_out;
    float* ws  = (float*)d_ws;

    ushort* Qt   = (ushort*)ws;
    ushort* Vbp  = (ushort*)(ws + OFF_VB);
    ushort* XRb  = (ushort*)(ws + OFF_XRB);
    float*  RSI  = ws + OFF_RSI;

    k_proj<<<BB * 32, 256, 0, stream>>>(x, wq, wv, bv, Qt, Vbp);
    k_rowstats<<<BB * 32, 512, 0, stream>>>(Qt, RSI);
    k_attn_pv<<<BB * 64, 512, 0, stream>>>(Qt, Vbp, RSI, XRb);
    k_final<<<BB * 32, 256, 0, stream>>>(x, XRb, wt, bt, gamma, beta, bn_mean, bn_var, out);
}

// Round 8
// 79.635 us; speedup vs baseline: 1.3340x; 1.3340x over previous
//
#include <hip/hip_runtime.h>
#include <hip/hip_bf16.h>
#include <math.h>

#define BB 16
#define CC 128
#define NN 2048
#define CQ 32   // C/4

typedef __attribute__((ext_vector_type(8))) short bf16x8;
typedef __attribute__((ext_vector_type(4))) float f32x4;

__device__ __forceinline__ ushort f2b(float f) {
    __hip_bfloat16 h = __float2bfloat16(f);
    return *reinterpret_cast<ushort*>(&h);
}
__device__ __forceinline__ float b2f(ushort u) {
    union { unsigned u; float f; } v; v.u = ((unsigned)u) << 16;
    return v.f;
}
__device__ __forceinline__ bf16x8 as_b8(uint4 u) {
    union { uint4 u; bf16x8 b; } v; v.u = u; return v.b;
}

// ---------------- workspace layout (float granularity offsets) ----------------
// Qt  : bf16 [B][N][32]   off 0          (524,288 fl)
// Vb  : bf16 [B][128][N]  off 524,288    (2,097,152 fl)
// XRb : bf16 [B][128][N]  off 2,621,440  (2,097,152 fl)
// RSI : f32  [B][N]       off 4,718,592  (32,768 fl)
#define OFF_VB  524288
#define OFF_XRB 2621440
#define OFF_RSI 4718592

// K1: MFMA projection. Qt[b,n,d] (d<32), Vb[b,d,n] = wv.x + bv.
__global__ __launch_bounds__(256) void k_proj(const float* __restrict__ x,
        const float* __restrict__ wq, const float* __restrict__ wv,
        const float* __restrict__ bv, ushort* __restrict__ Qt, ushort* __restrict__ Vb) {
    __shared__ ushort Wl[160][136];
    __shared__ ushort Xs[64][136];   // [n][c] bf16
    int bid = (blockIdx.x & 7) * 64 + (blockIdx.x >> 3);   // XCD-chunked swizzle
    int b  = bid >> 5;
    int n0 = (bid & 31) << 6;
    int tid = threadIdx.x;
    #pragma unroll
    for (int k = 0; k < 20; ++k) {
        int idx = k * 256 + tid;          // 5120 float4 chunks = 160x128 f32
        int r = idx >> 5, c4 = (idx & 31) << 2;
        const float* srcw = (r < 32) ? (wq + r * 128 + c4) : (wv + (r - 32) * 128 + c4);
        float4 w4 = *(const float4*)srcw;
        *(ushort4*)&Wl[r][c4] = make_ushort4(f2b(w4.x), f2b(w4.y), f2b(w4.z), f2b(w4.w));
    }
    const float* xb = x + (size_t)b * CC * NN;
    for (int idx = tid; idx < 2048; idx += 256) {
        int c = idx >> 4, n4 = (idx & 15) << 2;
        float4 xv = *(const float4*)&xb[c * NN + n0 + n4];
        Xs[n4][c]     = f2b(xv.x);
        Xs[n4 + 1][c] = f2b(xv.y);
        Xs[n4 + 2][c] = f2b(xv.z);
        Xs[n4 + 3][c] = f2b(xv.w);
    }
    __syncthreads();
    int w = tid >> 6, l = tid & 63, lr = l & 15, lg = l >> 4;
    f32x4 zero = {0.f, 0.f, 0.f, 0.f};
    int nn = n0 + w * 16 + lr;
    for (int dt = 0; dt < 10; ++dt) {
        f32x4 acc = zero;
        #pragma unroll
        for (int k = 0; k < 4; ++k) {
            bf16x8 a  = *(const bf16x8*)&Wl[dt * 16 + lr][k * 32 + lg * 8];
            bf16x8 bx = *(const bf16x8*)&Xs[w * 16 + lr][k * 32 + lg * 8];
            acc = __builtin_amdgcn_mfma_f32_16x16x32_bf16(a, bx, acc, 0, 0, 0);
        }
        if (dt < 2) {
            ushort4 p = make_ushort4(f2b(acc[0]), f2b(acc[1]), f2b(acc[2]), f2b(acc[3]));
            *(ushort4*)&Qt[(size_t)(b * NN + nn) * CQ + dt * 16 + lg * 4] = p;
        } else {
            #pragma unroll
            for (int i = 0; i < 4; ++i) {
                int vd = (dt - 2) * 16 + lg * 4 + i;
                Vb[(size_t)(b * CC + vd) * NN + nn] = f2b(acc[i] + bv[vd]);
            }
        }
    }
}

// K2: row softmax denominators (no max-subtract; E bounded). RSI = 1/rowsum.
__global__ __launch_bounds__(512) void k_rowstats(const ushort* __restrict__ Qt,
        float* __restrict__ RSI) {
    __shared__ ushort Qm[128][36];
    __shared__ float Sred[2][64];
    int bid = (blockIdx.x & 7) * 64 + (blockIdx.x >> 3);
    int b  = bid >> 5;
    int n0 = (bid & 31) << 6;
    int tid = threadIdx.x;
    int w = tid >> 6, l = tid & 63, lr = l & 15, lg = l >> 4;
    int wn = w & 3, wm = w >> 2;
    const ushort* Qtb = Qt + (size_t)b * NN * CQ;
    bf16x8 aq = *(const bf16x8*)&Qtb[(size_t)(n0 + wn * 16 + lr) * CQ + lg * 8];
    int sr = tid >> 2, sc = (tid & 3) * 8;
    uint4 q0 = *(const uint4*)&Qtb[(size_t)sr * CQ + sc];
    float S[4] = {0.f, 0.f, 0.f, 0.f};
    f32x4 zero = {0.f, 0.f, 0.f, 0.f};
    for (int t = 0; t < 16; ++t) {
        __syncthreads();
        *(uint4*)&Qm[sr][sc] = q0;
        __syncthreads();
        if (t < 15)
            q0 = *(const uint4*)&Qtb[(size_t)((t + 1) * 128 + sr) * CQ + sc];
        #pragma unroll
        for (int mi = 0; mi < 4; ++mi) {
            bf16x8 bq = *(const bf16x8*)&Qm[(wm * 4 + mi) * 16 + lr][lg * 8];
            f32x4 e = __builtin_amdgcn_mfma_f32_16x16x32_bf16(aq, bq, zero, 0, 0, 0);
            S[0] += __expf(e[0]); S[1] += __expf(e[1]);
            S[2] += __expf(e[2]); S[3] += __expf(e[3]);
        }
    }
    #pragma unroll
    for (int d = 1; d < 16; d <<= 1) {
        #pragma unroll
        for (int i = 0; i < 4; ++i) S[i] += __shfl_xor(S[i], d);
    }
    if (lr == 0) {
        #pragma unroll
        for (int i = 0; i < 4; ++i) Sred[wm][wn * 16 + lg * 4 + i] = S[i];
    }
    __syncthreads();
    if (tid < 64)
        RSI[b * NN + n0 + tid] = 1.f / (Sred[0][tid] + Sred[1][tid]);
}

// K3: attn + PV, 512 thr, m-tile 64, NT=128. R6 structure, stride-132 LDS
// (66 dwords == 2 mod 32 -> ~2-way conflicts), 8B LDS ops, 3 blocks/CU.
__global__ __launch_bounds__(512, 6) void k_attn_pv(const ushort* __restrict__ Qt,
        const ushort* __restrict__ Vb, const float* __restrict__ RSI,
        ushort* __restrict__ XRb) {
    __shared__ ushort Vs[128][132];  // [d][n]  row = 264B, 16B-misaligned on odd rows
    __shared__ ushort Ws[64][132];   // [m][n]
    __shared__ float rsi_s[128];
    __shared__ float csum[64];
    int bid = (blockIdx.x & 7) * 64 + (blockIdx.x >> 3);   // XCD-chunked swizzle
    int b  = bid >> 5;
    int m0 = (bid & 31) << 6;
    int tid = threadIdx.x;
    int w = tid >> 6, l = tid & 63, lr = l & 15, lg = l >> 4;
    const ushort* Qtb = Qt + (size_t)b * NN * CQ;
    const ushort* Vbb = Vb + (size_t)b * CC * NN;
    bf16x8 bm[4];
    #pragma unroll
    for (int mi = 0; mi < 4; ++mi)
        bm[mi] = *(const bf16x8*)&Qtb[(size_t)(m0 + mi * 16 + lr) * CQ + lg * 8];
    f32x4 zero = {0.f, 0.f, 0.f, 0.f};
    f32x4 pacc[4];
    #pragma unroll
    for (int mi = 0; mi < 4; ++mi) pacc[mi] = zero;
    float cs[4] = {0.f, 0.f, 0.f, 0.f};
    int dv = tid >> 2, hv = tid & 3;   // V staging: row dv, col-quarter hv (32 cols)
    for (int t = 0; t < 16; ++t) {
        int nt = t * 128;
        bf16x8 aq = *(const bf16x8*)&Qtb[(size_t)(nt + w * 16 + lr) * CQ + lg * 8];
        __syncthreads();                     // (a) prev PV done with Vs/Ws
        {
            const ushort* src = Vbb + (size_t)dv * NN + nt + hv * 32;
            #pragma unroll
            for (int j = 0; j < 4; ++j) {
                uint4 vv = *(const uint4*)(src + j * 8);        // b128 global
                *(uint2*)&Vs[dv][hv * 32 + j * 8]     = make_uint2(vv.x, vv.y);
                *(uint2*)&Vs[dv][hv * 32 + j * 8 + 4] = make_uint2(vv.z, vv.w);
            }
        }
        if (tid < 128) rsi_s[tid] = RSI[b * NN + nt + tid];
        __syncthreads();                     // (b) tile ready
        // ---- E phase: wave w owns n-strip [16w,16w+16) ----
        __builtin_amdgcn_s_setprio(1);
        f32x4 e[4];
        #pragma unroll
        for (int mi = 0; mi < 4; ++mi)
            e[mi] = __builtin_amdgcn_mfma_f32_16x16x32_bf16(aq, bm[mi], zero, 0, 0, 0);
        __builtin_amdgcn_s_setprio(0);
        int nb = w * 16 + lg * 4;
        float r0 = rsi_s[nb], r1 = rsi_s[nb + 1], r2 = rsi_s[nb + 2], r3 = rsi_s[nb + 3];
        #pragma unroll
        for (int mi = 0; mi < 4; ++mi) {
            float w0 = __expf(e[mi][0]) * r0;
            float w1 = __expf(e[mi][1]) * r1;
            float w2 = __expf(e[mi][2]) * r2;
            float w3 = __expf(e[mi][3]) * r3;
            cs[mi] += w0 + w1 + w2 + w3;
            *(ushort4*)&Ws[mi * 16 + lr][nb] =
                make_ushort4(f2b(w0), f2b(w1), f2b(w2), f2b(w3));   // 8B store
        }
        __syncthreads();                     // (c) Ws ready
        // ---- PV: wave w owns d in [16w, 16w+16), K = 128 ----
        __builtin_amdgcn_s_setprio(1);
        #pragma unroll
        for (int kk = 0; kk < 4; ++kk) {
            const ushort* vp = &Vs[w * 16 + lr][kk * 32 + lg * 8];
            uint2 v0 = *(const uint2*)vp;
            uint2 v1 = *(const uint2*)(vp + 4);
            bf16x8 va = as_b8(make_uint4(v0.x, v0.y, v1.x, v1.y));
            #pragma unroll
            for (int mi = 0; mi < 4; ++mi) {
                const ushort* wp = &Ws[mi * 16 + lr][kk * 32 + lg * 8];
                uint2 w0 = *(const uint2*)wp;
                uint2 w1 = *(const uint2*)(wp + 4);
                bf16x8 wb = as_b8(make_uint4(w0.x, w0.y, w1.x, w1.y));
                pacc[mi] = __builtin_amdgcn_mfma_f32_16x16x32_bf16(va, wb, pacc[mi], 0, 0, 0);
            }
        }
        __builtin_amdgcn_s_setprio(0);
    }
    // column sums: reduce over lg (shfl), then over 8 waves (LDS, aliased onto Vs)
    #pragma unroll
    for (int mi = 0; mi < 4; ++mi) {
        cs[mi] += __shfl_xor(cs[mi], 16);
        cs[mi] += __shfl_xor(cs[mi], 32);
    }
    __syncthreads();                         // all PV reads of Vs done
    float* csred = (float*)&Vs[0][0];        // [8][64] alias
    if (lg == 0) {
        #pragma unroll
        for (int mi = 0; mi < 4; ++mi) csred[w * 64 + mi * 16 + lr] = cs[mi];
    }
    __syncthreads();
    if (tid < 64) {
        float tot = 0.f;
        #pragma unroll
        for (int w2 = 0; w2 < 8; ++w2) tot += csred[w2 * 64 + tid];
        csum[tid] = 1.f / (1e-9f + tot);
    }
    __syncthreads();
    #pragma unroll
    for (int mi = 0; mi < 4; ++mi) {
        int ml = mi * 16 + lr;
        float inv = csum[ml];
        #pragma unroll
        for (int i = 0; i < 4; ++i) {
            int d = w * 16 + lg * 4 + i;
            XRb[(size_t)(b * CC + d) * NN + m0 + ml] = f2b(pacc[mi][i] * inv);
        }
    }
}

// K4: MFMA final: t = wt @ (x - XR); out = x + relu(t*fA + fB).
__global__ __launch_bounds__(256) void k_final(const float* __restrict__ x,
        const ushort* __restrict__ XRb, const float* __restrict__ wt,
        const float* __restrict__ bt, const float* __restrict__ gamma,
        const float* __restrict__ beta, const float* __restrict__ bn_mean,
        const float* __restrict__ bn_var, float* __restrict__ out) {
    __shared__ ushort Wl[128][136];
    __shared__ ushort Us[64][136];   // [n][c] bf16
    __shared__ float fAl[128], fBl[128];
    int bid = (blockIdx.x & 7) * 64 + (blockIdx.x >> 3);
    int b  = bid >> 5;
    int n0 = (bid & 31) << 6;
    int tid = threadIdx.x;
    #pragma unroll
    for (int k = 0; k < 16; ++k) {
        int idx = k * 256 + tid;          // 4096 float4 = 128x128 f32
        int r = idx >> 5, c4 = (idx & 31) << 2;
        float4 w4 = *(const float4*)&wt[r * 128 + c4];
        *(ushort4*)&Wl[r][c4] = make_ushort4(f2b(w4.x), f2b(w4.y), f2b(w4.z), f2b(w4.w));
    }
    if (tid < 128) {
        float A = gamma[tid] * rsqrtf(bn_var[tid] + 1e-5f);
        fAl[tid] = A;
        fBl[tid] = (bt[tid] - bn_mean[tid]) * A + beta[tid];
    }
    const float*  xb  = x   + (size_t)b * CC * NN;
    const ushort* xrb = XRb + (size_t)b * CC * NN;
    for (int idx = tid; idx < 2048; idx += 256) {
        int c = idx >> 4, n4 = (idx & 15) << 2;
        float4 xv = *(const float4*)&xb[c * NN + n0 + n4];
        ushort4 rv = *(const ushort4*)&xrb[c * NN + n0 + n4];
        Us[n4][c]     = f2b(xv.x - b2f(rv.x));
        Us[n4 + 1][c] = f2b(xv.y - b2f(rv.y));
        Us[n4 + 2][c] = f2b(xv.z - b2f(rv.z));
        Us[n4 + 3][c] = f2b(xv.w - b2f(rv.w));
    }
    __syncthreads();
    int w = tid >> 6, l = tid & 63, lr = l & 15, lg = l >> 4;
    f32x4 zero = {0.f, 0.f, 0.f, 0.f};
    int nn = n0 + w * 16 + lr;
    for (int dt = 0; dt < 8; ++dt) {
        f32x4 acc = zero;
        #pragma unroll
        for (int k = 0; k < 4; ++k) {
            bf16x8 a  = *(const bf16x8*)&Wl[dt * 16 + lr][k * 32 + lg * 8];
            bf16x8 bx = *(const bf16x8*)&Us[w * 16 + lr][k * 32 + lg * 8];
            acc = __builtin_amdgcn_mfma_f32_16x16x32_bf16(a, bx, acc, 0, 0, 0);
        }
        #pragma unroll
        for (int i = 0; i < 4; ++i) {
            int r = dt * 16 + lg * 4 + i;
            float t = acc[i] * fAl[r] + fBl[r];
            t = fmaxf(t, 0.f);
            out[(size_t)(b * CC + r) * NN + nn] = xb[r * NN + nn] + t;
        }
    }
}

extern "C" void kernel_launch(void* const* d_in, const int* in_sizes, int n_in,
                              void* d_out, int out_size, void* d_ws, size_t ws_size,
                              hipStream_t stream) {
    const float* x       = (const float*)d_in[0];
    const float* wq      = (const float*)d_in[1];
    const float* wv      = (const float*)d_in[2];
    const float* bv      = (const float*)d_in[3];
    const float* wt      = (const float*)d_in[4];
    const float* bt      = (const float*)d_in[5];
    const float* gamma   = (const float*)d_in[6];
    const float* beta    = (const float*)d_in[7];
    const float* bn_mean = (const float*)d_in[8];
    const float* bn_var  = (const float*)d_in[9];
    float* out = (float*)d_out;
    float* ws  = (float*)d_ws;

    ushort* Qt   = (ushort*)ws;
    ushort* Vbp  = (ushort*)(ws + OFF_VB);
    ushort* XRb  = (ushort*)(ws + OFF_XRB);
    float*  RSI  = ws + OFF_RSI;

    k_proj<<<BB * 32, 256, 0, stream>>>(x, wq, wv, bv, Qt, Vbp);
    k_rowstats<<<BB * 32, 512, 0, stream>>>(Qt, RSI);
    k_attn_pv<<<BB * 32, 512, 0, stream>>>(Qt, Vbp, RSI, XRb);
    k_final<<<BB * 32, 256, 0, stream>>>(x, XRb, wt, bt, gamma, beta, bn_mean, bn_var, out);
}